// Round 12
// baseline (179.215 us; speedup 1.0000x reference)
//
#include <hip/hip_runtime.h>
#include <math.h>

// Problem constants
#define B_N 2048
#define T_N 128
#define C_N 3
#define J_N 25
#define E_N 64
#define TC  (T_N*C_N)    // 384 rows per batch
#define TCJ (TC*J_N)     // 9600 floats per batch
#define NQ4 (TCJ/4)      // 2400 float4 per batch
#define NC  256          // contracted size (ncomp <= 256 after 3 unions)

// Workspace layout (float offsets). ~17.4 MiB.
#define D_OFF      0                       // D [2048*2048] f32 (raw-h distances)
#define H_OFF      (B_N*B_N)               // h [2048*25]
#define BLO_OFF    (H_OFF + B_N*J_N)       // per-block lo [2048]
#define BHI_OFF    (BLO_OFF + B_N)         // per-block hi [2048]
#define DEATHS_OFF (BHI_OFF + B_N)         // f32 deaths[2047]
#define BEST_OFF   (DEATHS_OFF + B_N)      // u64 best[2][2048] (even -> 8B aligned)
#define COMP_OFF   (BEST_OFF + 4*B_N)      // u32 comp[2][2048]
#define GC_OFF     (COMP_OFF + 2*B_N)      // u32 gcnt[2]
#define TK_OFF     (GC_OFF + 2)            // u32 ticket
#define DC_OFF     (GC_OFF + 4)            // u32 Dc[256*256] contracted min-dist (f32 bits)

typedef unsigned long long u64;
#define U64MAX 0xFFFFFFFFFFFFFFFFull
#define U32INF 0xFFFFFFFFu

// One block per batch. Coalesced float4 grid-stride (stride 250 preserves
// j-residue mod 25), register accumulate, tiny LDS reduce. Per-block lo/hi.
__global__ void __launch_bounds__(256) k_reduce(const float* __restrict__ x,
                                                float* __restrict__ ws) {
    __shared__ float4 part[250];
    __shared__ float S[100];
    __shared__ float Mj[25];
    const int t = threadIdx.x, b = blockIdx.x;
    const float4* x4 = (const float4*)(x + (size_t)b * TCJ);
    if (t < 250) {
        float4 a; a.x = a.y = a.z = a.w = 0.f;
        for (int idx = t; idx < NQ4; idx += 250) {
            float4 v = x4[idx];
            a.x += v.x; a.y += v.y; a.z += v.z; a.w += v.w;
        }
        part[t] = a;
    }
    __syncthreads();
    if (t < 25) {
        float4 s = part[t];
        #pragma unroll
        for (int g = 1; g < 10; ++g) {
            float4 v = part[t + 25 * g];
            s.x += v.x; s.y += v.y; s.z += v.z; s.w += v.w;
        }
        S[4*t] = s.x; S[4*t+1] = s.y; S[4*t+2] = s.z; S[4*t+3] = s.w;
    }
    __syncthreads();
    if (t < 25) Mj[t] = (S[t] + S[t+25] + S[t+50] + S[t+75]) * (1.0f / 384.0f);
    __syncthreads();
    if (t < 25) {
        float mj = Mj[t], acc = 0.f;
        #pragma unroll
        for (int i = 0; i < J_N; ++i) { float d = Mj[i] - mj; acc += d * d; }
        float hv = sqrtf(acc);
        ws[H_OFF + b * J_N + t] = hv;
        S[t] = hv;
    }
    __syncthreads();
    if (t == 0) {
        float lo = S[0], hi = S[0];
        #pragma unroll
        for (int i = 1; i < J_N; ++i) { lo = fminf(lo, S[i]); hi = fmaxf(hi, S[i]); }
        ws[BLO_OFF + b] = lo;
        ws[BHI_OFF + b] = hi;
    }
}

// Fused dist + round-0 scan. 128 blocks x 16 rows; wave = one row.
// Two 1024-column mega-tiles of h staged in LDS; A-row in registers. Each
// wave computes its row's distances, writes D, keeps the running min edge
// key in-register -> shuffle-reduce -> best[0][row]. Seeds comp/gcnt/ticket/Dc.
__global__ void __launch_bounds__(1024) k_distscan(float* __restrict__ ws) {
    __shared__ float A[16][26];
    __shared__ float Bsh[1024 * J_N];   // 100 KB
    const int t = threadIdx.x, blk = blockIdx.x;
    const int ty = t >> 6, tx = t & 63;
    const float* h = ws + H_OFF;
    const int row0 = blk * 16;
    for (int idx = t; idx < 16 * J_N; idx += 1024)
        A[idx / J_N][idx % J_N] = h[(row0 + idx / J_N) * J_N + idx % J_N];
    if (blk < 64) ((unsigned*)(ws + DC_OFF))[blk * 1024 + t] = U32INF;
    if (blk == 0) {
        unsigned* gc = (unsigned*)(ws + COMP_OFF);
        gc[t] = (unsigned)t; gc[t + 1024] = (unsigned)(t + 1024);
        if (t == 0) {
            ((unsigned*)(ws + GC_OFF))[0] = 0u;
            ((unsigned*)(ws + GC_OFF))[1] = 0u;
            *(unsigned*)(ws + TK_OFF) = 0u;
        }
    }
    const int row = row0 + ty;
    float ar[J_N];
    u64 bestk = U64MAX;
    float* D = ws + D_OFF;
    for (int mt = 0; mt < 2; ++mt) {
        __syncthreads();   // protect Bsh (and cover A on mt=0)
        for (int idx = t; idx < 1024 * J_N; idx += 1024)
            Bsh[idx] = h[mt * 1024 * J_N + idx];
        __syncthreads();
        if (mt == 0) {
            #pragma unroll
            for (int k = 0; k < J_N; ++k) ar[k] = A[ty][k];
        }
        #pragma unroll 4
        for (int cc = 0; cc < 16; ++cc) {
            const int col = mt * 1024 + cc * 64 + tx;
            const float* bp = &Bsh[(cc * 64 + tx) * J_N];
            float acc = 0.f;
            #pragma unroll
            for (int k = 0; k < J_N; ++k) { float d = ar[k] - bp[k]; acc += d * d; }
            float dist = sqrtf(fmaxf(acc, 1e-12f));
            D[(size_t)row * B_N + col] = dist;
            if (col != row) {
                unsigned a = min((unsigned)row, (unsigned)col);
                unsigned b2 = max((unsigned)row, (unsigned)col);
                u64 key = ((u64)__float_as_uint(dist) << 32) | (a << 11) | b2;
                if (key < bestk) bestk = key;
            }
        }
    }
    #pragma unroll
    for (int off = 32; off; off >>= 1) {
        u64 o = __shfl_down(bestk, off);
        if (o < bestk) bestk = o;
    }
    if (tx == 0) ((u64*)(ws + BEST_OFF))[row] = bestk;
}

// One Boruvka round: replicated-in-LDS union of best[par_in], then scan with
// the fresh LDS comp -> best[par_in^1]. Reuse pruning: if a row's previous
// best edge is still outgoing, it remains the row min. blk0 persists state.
__global__ void __launch_bounds__(1024) k_round(float* __restrict__ ws, int par_in) {
    unsigned* gcnt = (unsigned*)(ws + GC_OFF);
    const unsigned base = gcnt[par_in];
    if (base >= B_N - 1) return;   // converged: stub
    __shared__ __align__(16) unsigned comp[B_N];  // 8 KB
    __shared__ u64 cb[B_N];                       // 16 KB
    __shared__ unsigned par[B_N];                 // 8 KB
    __shared__ unsigned cnt_s;
    const int t = threadIdx.x, blk = blockIdx.x;
    const unsigned* gcomp_in = (const unsigned*)(ws + COMP_OFF) + par_in * B_N;
    unsigned* gcomp_out = (unsigned*)(ws + COMP_OFF) + (par_in ^ 1) * B_N;
    const u64* bin = (const u64*)(ws + BEST_OFF) + par_in * B_N;
    u64* bout = (u64*)(ws + BEST_OFF) + (par_in ^ 1) * B_N;
    float* deaths = ws + DEATHS_OFF;

    if (t == 0) cnt_s = 0u;
    comp[t] = gcomp_in[t]; comp[t + 1024] = gcomp_in[t + 1024];
    cb[t] = U64MAX; cb[t + 1024] = U64MAX;
    __syncthreads();
    #pragma unroll
    for (int i = t; i < B_N; i += 1024) {
        u64 bk = bin[i];
        if (bk != U64MAX) atomicMin(&cb[comp[i]], bk);
    }
    __syncthreads();
    #pragma unroll
    for (int c = t; c < B_N; c += 1024) {
        u64 k = cb[c];
        unsigned p = (unsigned)c;
        if (k != U64MAX) {
            unsigned a  = (unsigned)((k >> 11) & 0x7FFu);
            unsigned b2 = (unsigned)(k & 0x7FFu);
            unsigned ca = comp[a], cbv = comp[b2];
            unsigned c2 = (ca == (unsigned)c) ? cbv : ca;
            p = c2;
            if (!(cb[c2] == k && c2 < (unsigned)c)) {
                unsigned li = atomicAdd(&cnt_s, 1u);
                if (blk == 0) deaths[base + li] = __uint_as_float((unsigned)(k >> 32));
            }
        }
        par[c] = p;
    }
    __syncthreads();
    #pragma unroll
    for (int c = t; c < B_N; c += 1024) {
        unsigned p = par[c];
        if (p != (unsigned)c && par[p] == (unsigned)c && (unsigned)c < p) par[c] = (unsigned)c;
    }
    __syncthreads();
    #pragma unroll
    for (int c = t; c < B_N; c += 1024) {
        unsigned r = par[c];
        while (true) { unsigned pr = par[r]; if (pr == r) break; r = pr; }
        par[c] = r;
    }
    __syncthreads();
    #pragma unroll
    for (int i = t; i < B_N; i += 1024) comp[i] = par[comp[i]];
    __syncthreads();
    const unsigned newbase = base + cnt_s;
    if (blk == 0) {
        gcomp_out[t] = comp[t]; gcomp_out[t + 1024] = comp[t + 1024];
        if (t == 0) { gcnt[par_in ^ 1] = newbase; if (newbase >= B_N - 1) gcnt[par_in] = newbase; }
    }
    if (newbase >= B_N - 1) return;

    // ---- scan (one wave per row) with reuse pruning ----
    const int w = t >> 6, lane = t & 63;
    const int row = blk * 16 + w;
    const unsigned ci = comp[row];
    u64 prev = bin[row];
    {
        unsigned pa = (unsigned)((prev >> 11) & 0x7FFu);
        unsigned pb = (unsigned)(prev & 0x7FFu);
        unsigned jo = (pa == (unsigned)row) ? pb : pa;
        if (comp[jo] != ci) {          // still outgoing -> still the min
            if (lane == 0) bout[row] = prev;
            return;                    // wave-uniform exit
        }
    }
    const float4* row4 = (const float4*)(ws + D_OFF + (size_t)row * B_N);
    const uint4* comp4 = (const uint4*)comp;
    u64 best = U64MAX;
    #pragma unroll
    for (int k = 0; k < 8; ++k) {
        const int q = k * 64 + lane;
        float4 w4 = row4[q];
        uint4  c4 = comp4[q];
        const unsigned j0 = (unsigned)(q * 4);
        float wv[4] = {w4.x, w4.y, w4.z, w4.w};
        unsigned cv[4] = {c4.x, c4.y, c4.z, c4.w};
        #pragma unroll
        for (int m = 0; m < 4; ++m) {
            if (cv[m] != ci) {
                unsigned j = j0 + m;
                unsigned a = min((unsigned)row, j), b2 = max((unsigned)row, j);
                u64 key = ((u64)__float_as_uint(wv[m]) << 32) | (a << 11) | b2;
                if (key < best) best = key;
            }
        }
    }
    #pragma unroll
    for (int off = 32; off; off >>= 1) {
        u64 o = __shfl_down(best, off);
        if (o < best) best = o;
    }
    if (lane == 0) bout[row] = best;
}

// 3rd union + contraction to 256x256 + (winner block) contracted Boruvka +
// structure layer, all in ONE kernel via last-block ticket.
// Safety vs round-4's failed fusion: ONE __threadfence per block (after
// __syncthreads drained all global ops), ticket is the only same-address
// atomic. Round-3 deaths use deterministic prefix-scan slots so all blocks
// write bit-identical values to identical slots (benign races; the winner
// reads only values it wrote itself). Dc merged via device-scope atomicMin;
// winner reads it back with device-scope atomic loads.
__global__ void __launch_bounds__(1024) k_round3cf(float* __restrict__ ws,
                                                   const float* __restrict__ centres,
                                                   const float* __restrict__ sharp,
                                                   float* __restrict__ out) {
    __shared__ __align__(16) unsigned char arena[135168];   // 132 KB overlay arena
    __shared__ unsigned cnt_s, csum[16], lastflag, base_s;
    __shared__ float redlo[16], redhi[16];
    // Phase A-C layout:
    unsigned* comp  = (unsigned*)arena;                 // u32[2048]
    u64*      cb    = (u64*)(arena + 8192);             // u64[2048]
    unsigned* par   = (unsigned*)(arena + 24576);       // u32[2048]
    unsigned* cflag = (unsigned*)(arena + 32768);       // u32[2048]
    unsigned* pd    = (unsigned*)(arena + 40960);       // u32[16*256]
    unsigned* af    = (unsigned*)(arena + 57344);       // u32[2048] add flags -> slots
    float*    dwv   = (float*)(arena + 65536);          // f32[2048] edge weights
    // Finish overlay (winner only, after ticket):
    unsigned short* Dcs = (unsigned short*)arena;       // u16[256*256] = 128 KB
    u64*      cbf   = (u64*)(arena + 131072);           // u64[256]
    unsigned* parf  = (unsigned*)(arena + 133120);      // u32[256]
    unsigned* ccomp = (unsigned*)(arena + 134144);      // u32[256]

    const int t = threadIdx.x, blk = blockIdx.x;
    const unsigned lane = t & 63, w = t >> 6;
    unsigned* gcnt = (unsigned*)(ws + GC_OFF);
    float* deaths = ws + DEATHS_OFF;
    unsigned* gDc = (unsigned*)(ws + DC_OFF);
    const unsigned base = gcnt[0];
    unsigned newbase = base;

    if (base < B_N - 1) {
        // ---- phase A: union of best[parity 0] ----
        const unsigned* gcomp_in = (const unsigned*)(ws + COMP_OFF);
        const u64* bin = (const u64*)(ws + BEST_OFF);
        if (t == 0) cnt_s = 0u;
        comp[t] = gcomp_in[t]; comp[t + 1024] = gcomp_in[t + 1024];
        cb[t] = U64MAX; cb[t + 1024] = U64MAX;
        __syncthreads();
        #pragma unroll
        for (int i = t; i < B_N; i += 1024) {
            u64 bk = bin[i];
            if (bk != U64MAX) atomicMin(&cb[comp[i]], bk);
        }
        __syncthreads();
        #pragma unroll
        for (int c = t; c < B_N; c += 1024) {
            u64 k = cb[c];
            unsigned p = (unsigned)c, flag = 0u;
            float dw = 0.f;
            if (k != U64MAX) {
                unsigned a  = (unsigned)((k >> 11) & 0x7FFu);
                unsigned b2 = (unsigned)(k & 0x7FFu);
                unsigned ca = comp[a], cbv = comp[b2];
                unsigned c2 = (ca == (unsigned)c) ? cbv : ca;
                p = c2;
                if (!(cb[c2] == k && c2 < (unsigned)c)) {
                    flag = 1u; dw = __uint_as_float((unsigned)(k >> 32));
                    atomicAdd(&cnt_s, 1u);
                }
            }
            par[c] = p; af[c] = flag; dwv[c] = dw;
        }
        __syncthreads();
        #pragma unroll
        for (int c = t; c < B_N; c += 1024) {
            unsigned p = par[c];
            if (p != (unsigned)c && par[p] == (unsigned)c && (unsigned)c < p) par[c] = (unsigned)c;
        }
        __syncthreads();
        #pragma unroll
        for (int c = t; c < B_N; c += 1024) {
            unsigned r = par[c];
            while (true) { unsigned pr = par[r]; if (pr == r) break; r = pr; }
            par[c] = r;
        }
        __syncthreads();
        #pragma unroll
        for (int i = t; i < B_N; i += 1024) comp[i] = par[comp[i]];
        // deterministic death slots: exclusive prefix over af (c-order)
        unsigned f0 = af[2 * t], f1 = af[2 * t + 1];
        unsigned s2 = f0 + f1, sc2 = s2;
        #pragma unroll
        for (int off = 1; off < 64; off <<= 1) {
            unsigned v = __shfl_up(sc2, off);
            if (lane >= (unsigned)off) sc2 += v;
        }
        if (lane == 63) csum[w] = sc2;
        __syncthreads();
        if (t < 16) {
            unsigned v = csum[t], acc = v;
            #pragma unroll
            for (int off = 1; off < 16; off <<= 1) {
                unsigned u2 = __shfl_up(acc, off);
                if (t >= off) acc += u2;
            }
            csum[t] = acc - v;   // exclusive
        }
        __syncthreads();
        {
            unsigned off0 = csum[w] + (sc2 - s2);
            af[2 * t]     = f0 ? off0        : U32INF;
            af[2 * t + 1] = f1 ? (off0 + f0) : U32INF;
        }
        __syncthreads();
        #pragma unroll
        for (int c = t; c < B_N; c += 1024) {
            unsigned s = af[c];
            if (s != U32INF) deaths[base + s] = dwv[c];   // identical across blocks
        }
        newbase = base + cnt_s;

        if (newbase < B_N - 1) {
            // ---- phase B: rank map (deterministic across blocks) ----
            cflag[t] = 0u; cflag[t + 1024] = 0u;
            __syncthreads();
            cflag[comp[t]] = 1u; cflag[comp[t + 1024]] = 1u;
            __syncthreads();
            unsigned g0 = cflag[2 * t], g1 = cflag[2 * t + 1];
            unsigned s3 = g0 + g1, sc3 = s3;
            #pragma unroll
            for (int off = 1; off < 64; off <<= 1) {
                unsigned v = __shfl_up(sc3, off);
                if (lane >= (unsigned)off) sc3 += v;
            }
            if (lane == 63) csum[w] = sc3;
            __syncthreads();
            if (t < 16) {
                unsigned v = csum[t], acc = v;
                #pragma unroll
                for (int off = 1; off < 16; off <<= 1) {
                    unsigned u2 = __shfl_up(acc, off);
                    if (t >= off) acc += u2;
                }
                csum[t] = acc - v;
            }
            __syncthreads();
            {
                unsigned off0 = csum[w] + (sc3 - s3);
                if (g0) cflag[2 * t] = off0;
                if (g1) cflag[2 * t + 1] = off0 + g0;
            }
            __syncthreads();
            // ---- phase C: contract this block's 16 rows into pd[16][256] ----
            #pragma unroll
            for (int i = 0; i < 4; ++i) pd[i * 1024 + t] = U32INF;
            __syncthreads();
            const int row = blk * 16 + (int)w;
            const unsigned ci = comp[row];
            {
                const float4* row4 = (const float4*)(ws + D_OFF + (size_t)row * B_N);
                const uint4* comp4 = (const uint4*)comp;
                #pragma unroll
                for (int k = 0; k < 8; ++k) {
                    const int q = k * 64 + (int)lane;
                    float4 w4 = row4[q];
                    uint4  c4 = comp4[q];
                    float wv[4] = {w4.x, w4.y, w4.z, w4.w};
                    unsigned cv[4] = {c4.x, c4.y, c4.z, c4.w};
                    #pragma unroll
                    for (int m = 0; m < 4; ++m) {
                        if (cv[m] != ci) atomicMin(&pd[w * NC + cflag[cv[m]]], __float_as_uint(wv[m]));
                    }
                }
            }
            __syncthreads();
            const unsigned ri = cflag[ci];
            for (int j2 = (int)lane; j2 < NC; j2 += 64) {
                unsigned v = pd[w * NC + j2];
                if (v != U32INF) atomicMin(&gDc[ri * NC + j2], v);
            }
        }
    }

    // ---- ticket: last block to arrive runs the finish ----
    __syncthreads();   // drains this block's global stores/atomics (vmcnt 0)
    if (t == 0) {
        __threadfence();
        unsigned prev = atomicAdd((unsigned*)(ws + TK_OFF), 1u);
        lastflag = (prev == gridDim.x - 1) ? 1u : 0u;
    }
    __syncthreads();
    if (!lastflag) return;

    // ---- winner: contracted Boruvka on Dc (bf16-quantized, 128 KB LDS) ----
    if (newbase < B_N - 1) {
        #pragma unroll
        for (int i = 0; i < 64; ++i) {
            unsigned v = __hip_atomic_load(&gDc[i * 1024 + t], __ATOMIC_RELAXED,
                                           __HIP_MEMORY_SCOPE_AGENT);
            Dcs[i * 1024 + t] = (unsigned short)(v >> 16);   // U32INF -> 0xFFFF
        }
        if (t < NC) ccomp[t] = (unsigned)t;
        if (t == 0) base_s = newbase;
        __syncthreads();
        for (int iter = 0; iter < 8; ++iter) {
            if (t < NC) cbf[t] = U64MAX;
            if (t == 0) cnt_s = 0u;
            __syncthreads();
            #pragma unroll
            for (int q = 0; q < 16; ++q) {
                const int r = (int)w * 16 + q;
                const unsigned cc = ccomp[r];
                u64 key = U64MAX;
                #pragma unroll
                for (int hh = 0; hh < 4; ++hh) {
                    const int c = (int)lane + hh * 64;
                    unsigned wv = Dcs[r * NC + c];
                    if (wv != 0xFFFFu && ccomp[c] != cc) {
                        unsigned a = min((unsigned)r, (unsigned)c);
                        unsigned b2 = max((unsigned)r, (unsigned)c);
                        u64 k2 = ((u64)wv << 32) | (a << 8) | b2;
                        if (k2 < key) key = k2;
                    }
                }
                #pragma unroll
                for (int off = 32; off; off >>= 1) {
                    u64 o = __shfl_down(key, off);
                    if (o < key) key = o;
                }
                if (lane == 0 && key != U64MAX) atomicMin(&cbf[cc], key);
            }
            __syncthreads();
            bool add = false; float dw = 0.f;
            if (t < NC) {
                u64 k = cbf[t];
                unsigned p = (unsigned)t;
                if (k != U64MAX) {
                    unsigned a = (unsigned)((k >> 8) & 255u), b2 = (unsigned)(k & 255u);
                    unsigned ca = ccomp[a], cbv = ccomp[b2];
                    unsigned c2 = (ca == (unsigned)t) ? cbv : ca;
                    p = c2;
                    if (!(cbf[c2] == k && c2 < (unsigned)t)) {
                        add = true;
                        dw = __uint_as_float((unsigned)(k >> 32) << 16);
                    }
                }
                parf[t] = p;
            }
            __syncthreads();
            if (t < NC) {
                unsigned pp = parf[t];
                if (pp != (unsigned)t && parf[pp] == (unsigned)t && (unsigned)t < pp) parf[t] = (unsigned)t;
            }
            __syncthreads();
            if (t < NC) {
                unsigned r2 = parf[t];
                while (parf[r2] != r2) r2 = parf[r2];
                parf[t] = r2;
            }
            __syncthreads();
            if (t < NC) {
                if (add) { unsigned li = atomicAdd(&cnt_s, 1u); deaths[base_s + li] = dw; }
                ccomp[t] = parf[ccomp[t]];
            }
            __syncthreads();
            if (t == 0) base_s += cnt_s;
            __syncthreads();
            if (base_s >= B_N - 1) break;
        }
        __syncthreads();
    }

    // ---- struct phase ----
    float lo = INFINITY, hi = -INFINITY;
    #pragma unroll
    for (int i = t; i < B_N; i += 1024) {
        lo = fminf(lo, ws[BLO_OFF + i]);
        hi = fmaxf(hi, ws[BHI_OFF + i]);
    }
    #pragma unroll
    for (int off = 32; off; off >>= 1) {
        lo = fminf(lo, __shfl_down(lo, off));
        hi = fmaxf(hi, __shfl_down(hi, off));
    }
    if (lane == 0) { redlo[w] = lo; redhi[w] = hi; }
    __syncthreads();
    lo = redlo[0]; hi = redhi[0];
    #pragma unroll
    for (int k = 1; k < 16; ++k) { lo = fminf(lo, redlo[k]); hi = fmaxf(hi, redhi[k]); }
    float rng = hi - lo;
    float rinv = (rng > 1e-8f) ? 1.0f / rng : 0.0f;

    for (int e = (int)w; e < E_N; e += 16) {
        const float c0 = centres[e * 2], c1 = centres[e * 2 + 1];
        const float s0 = sharp[e * 2],   s1 = sharp[e * 2 + 1];
        const float s1sq = s1 * s1;
        float acc = 0.f;
        for (int p = (int)lane; p < B_N - 1; p += 64) {
            float d = deaths[p] * rinv - c1;
            acc += expf(-s1sq * d * d);
        }
        #pragma unroll
        for (int off = 32; off; off >>= 1) acc += __shfl_down(acc, off);
        if (lane == 0) out[e] = expf(-s0 * s0 * c0 * c0) * acc;
    }
}

extern "C" void kernel_launch(void* const* d_in, const int* in_sizes, int n_in,
                              void* d_out, int out_size, void* d_ws, size_t ws_size,
                              hipStream_t stream) {
    const float* x       = (const float*)d_in[0];
    const float* centres = (const float*)d_in[1];
    const float* sharp   = (const float*)d_in[2];
    float* out = (float*)d_out;
    float* ws  = (float*)d_ws;

    hipLaunchKernelGGL(k_reduce,   dim3(B_N),  dim3(256),  0, stream, x, ws);
    hipLaunchKernelGGL(k_distscan, dim3(128),  dim3(1024), 0, stream, ws);
    hipLaunchKernelGGL(k_round,    dim3(128),  dim3(1024), 0, stream, ws, 0);
    hipLaunchKernelGGL(k_round,    dim3(128),  dim3(1024), 0, stream, ws, 1);
    hipLaunchKernelGGL(k_round3cf, dim3(128),  dim3(1024), 0, stream, ws, centres, sharp, out);
}